// Round 1
// baseline (94.661 us; speedup 1.0000x reference)
//
#include <hip/hip_runtime.h>

#define SEQL 512
#define PREDL 96
#define NB 9          // 1 + 2*4 basis functions (DC, cos/sin k=1..4)
#define WBPAD 12      // padded stride for WB rows

static __device__ __constant__ double TWO_PI_OVER_S = 6.283185307179586476925286766559 / (double)SEQL;

// ---------------- setup kernel 1: basis table (j-major: tbl[j*512 + s]) ----------
__global__ void basis_kernel(float* __restrict__ tbl) {
    int s = threadIdx.x;
    if (s >= SEQL) return;
    tbl[0 * SEQL + s] = 1.0f;
    #pragma unroll
    for (int k = 1; k <= 4; ++k) {
        double ang = TWO_PI_OVER_S * (double)(k * s);
        tbl[(2 * k - 1) * SEQL + s] = (float)cos(ang);
        tbl[(2 * k    ) * SEQL + s] = (float)sin(ang);
    }
}

// ---------------- setup kernel 2: WB[p][j] = basis_j . W[p]  (unscaled) ----------
__global__ __launch_bounds__(64)
void wb_kernel(const float* __restrict__ W, const float* __restrict__ tbl,
               float* __restrict__ wb) {
    int p = blockIdx.x;          // 0..95
    int lane = threadIdx.x;      // 0..63
    const float* wr = W + (size_t)p * SEQL + lane * 8;
    float4 wa = *(const float4*)(wr);
    float4 wz = *(const float4*)(wr + 4);
    float wv[8] = {wa.x, wa.y, wa.z, wa.w, wz.x, wz.y, wz.z, wz.w};
    float c[NB];
    #pragma unroll
    for (int j = 0; j < NB; ++j) {
        const float* bj = tbl + j * SEQL + lane * 8;
        float4 b0 = *(const float4*)bj;
        float4 b1 = *(const float4*)(bj + 4);
        float bb[8] = {b0.x, b0.y, b0.z, b0.w, b1.x, b1.y, b1.z, b1.w};
        float acc = 0.f;
        #pragma unroll
        for (int e = 0; e < 8; ++e) acc += wv[e] * bb[e];
        c[j] = acc;
    }
    #pragma unroll
    for (int m = 1; m < 64; m <<= 1) {
        #pragma unroll
        for (int j = 0; j < NB; ++j) c[j] += __shfl_xor(c[j], m, 64);
    }
    if (lane == 0) {
        #pragma unroll
        for (int j = 0; j < NB; ++j) wb[p * WBPAD + j] = c[j];
    }
}

// ---------------- main kernel: one wave per row ----------------------------------
__global__ __launch_bounds__(256)
void detrend_kernel(const float* __restrict__ x, const float* __restrict__ bias,
                    const float* __restrict__ tbl, const float* __restrict__ wb,
                    float* __restrict__ fc, float* __restrict__ resid, int nrows) {
    const int lane = threadIdx.x & 63;
    const int wid  = threadIdx.x >> 6;
    const int wpb  = blockDim.x >> 6;
    const int gw   = blockIdx.x * wpb + wid;
    const int nw   = gridDim.x * wpb;

    // loop-invariant: this lane's 8 basis values per j (72 VGPRs)
    float bas[NB][8];
    #pragma unroll
    for (int j = 0; j < NB; ++j) {
        const float* bj = tbl + j * SEQL + lane * 8;
        float4 b0 = *(const float4*)bj;
        float4 b1 = *(const float4*)(bj + 4);
        bas[j][0] = b0.x; bas[j][1] = b0.y; bas[j][2] = b0.z; bas[j][3] = b0.w;
        bas[j][4] = b1.x; bas[j][5] = b1.y; bas[j][6] = b1.z; bas[j][7] = b1.w;
    }
    // loop-invariant: forecast weights for this lane's output columns
    const int p0 = lane;        // 0..63 (<96, always valid)
    const int p1 = 64 + lane;   // valid for lane<32
    float wb0[NB], wb1[NB], bv0, bv1 = 0.f;
    #pragma unroll
    for (int j = 0; j < NB; ++j) wb0[j] = wb[p0 * WBPAD + j];
    bv0 = bias[p0];
    if (lane < 32) {
        #pragma unroll
        for (int j = 0; j < NB; ++j) wb1[j] = wb[p1 * WBPAD + j];
        bv1 = bias[p1];
    }

    for (int r = gw; r < nrows; r += nw) {
        const float* xr = x + (size_t)r * SEQL + lane * 8;
        float4 xa = *(const float4*)xr;
        float4 xb = *(const float4*)(xr + 4);
        float xv[8] = {xa.x, xa.y, xa.z, xa.w, xb.x, xb.y, xb.z, xb.w};

        // 9 partial dots over this lane's 8 elements
        float c[NB];
        #pragma unroll
        for (int j = 0; j < NB; ++j) c[j] = 0.f;
        #pragma unroll
        for (int e = 0; e < 8; ++e) {
            #pragma unroll
            for (int j = 0; j < NB; ++j) c[j] += xv[e] * bas[j][e];
        }
        // full-wave butterfly: every lane ends with all 9 sums
        #pragma unroll
        for (int m = 1; m < 64; m <<= 1) {
            #pragma unroll
            for (int j = 0; j < NB; ++j) c[j] += __shfl_xor(c[j], m, 64);
        }
        // irfft scaling: DC 1/S, others 2/S
        c[0] *= (1.0f / SEQL);
        #pragma unroll
        for (int j = 1; j < NB; ++j) c[j] *= (2.0f / SEQL);

        // reconstruct trend, write resid
        float rv[8];
        #pragma unroll
        for (int e = 0; e < 8; ++e) {
            float t = 0.f;
            #pragma unroll
            for (int j = 0; j < NB; ++j) t += c[j] * bas[j][e];
            rv[e] = xv[e] - t;
        }
        float* rr = resid + (size_t)r * SEQL + lane * 8;
        *(float4*)rr       = make_float4(rv[0], rv[1], rv[2], rv[3]);
        *(float4*)(rr + 4) = make_float4(rv[4], rv[5], rv[6], rv[7]);

        // forecast: 96 outputs = rank-9 combo
        float* fr = fc + (size_t)r * PREDL;
        float f0 = bv0;
        #pragma unroll
        for (int j = 0; j < NB; ++j) f0 += c[j] * wb0[j];
        fr[p0] = f0;
        if (lane < 32) {
            float f1 = bv1;
            #pragma unroll
            for (int j = 0; j < NB; ++j) f1 += c[j] * wb1[j];
            fr[p1] = f1;
        }
    }
}

extern "C" void kernel_launch(void* const* d_in, const int* in_sizes, int n_in,
                              void* d_out, int out_size, void* d_ws, size_t ws_size,
                              hipStream_t stream) {
    const float* x = (const float*)d_in[0];
    const float* W = (const float*)d_in[1];
    const float* b = (const float*)d_in[2];
    float* fc = (float*)d_out;
    const int nrows = in_sizes[0] / SEQL;            // 64*1024 = 65536
    float* resid = fc + (size_t)nrows * PREDL;       // outputs concatenated flat
    float* tbl = (float*)d_ws;                       // 9*512 floats
    float* wb  = tbl + NB * SEQL;                    // 96*12 floats

    hipLaunchKernelGGL(basis_kernel, dim3(1), dim3(SEQL), 0, stream, tbl);
    hipLaunchKernelGGL(wb_kernel, dim3(PREDL), dim3(64), 0, stream, W, tbl, wb);
    hipLaunchKernelGGL(detrend_kernel, dim3(4096), dim3(256), 0, stream,
                       x, b, tbl, wb, fc, resid, nrows);
}

// Round 3
// 64.551 us; speedup vs baseline: 1.4665x; 1.4665x over previous
//
#include <hip/hip_runtime.h>

#define SEQL 512
#define PREDL 96
#define NB 9          // 1 + 2*4 basis functions (DC, cos/sin k=1..4)
#define WBPAD 12      // padded stride for WB rows
#define RU 4          // row unroll per wave per iteration

typedef float fvec4 __attribute__((ext_vector_type(4)));

static __device__ __constant__ double TWO_PI_OVER_S = 6.283185307179586476925286766559 / (double)SEQL;

// ---------------- setup kernel 1: basis table (j-major: tbl[j*512 + s]) ----------
__global__ void basis_kernel(float* __restrict__ tbl) {
    int s = threadIdx.x;
    if (s >= SEQL) return;
    tbl[0 * SEQL + s] = 1.0f;
    #pragma unroll
    for (int k = 1; k <= 4; ++k) {
        double ang = TWO_PI_OVER_S * (double)(k * s);
        tbl[(2 * k - 1) * SEQL + s] = (float)cos(ang);
        tbl[(2 * k    ) * SEQL + s] = (float)sin(ang);
    }
}

// ---------------- setup kernel 2: WB[p][j] = basis_j . W[p]  (unscaled) ----------
__global__ __launch_bounds__(64)
void wb_kernel(const float* __restrict__ W, const float* __restrict__ tbl,
               float* __restrict__ wb) {
    int p = blockIdx.x;          // 0..95
    int lane = threadIdx.x;      // 0..63
    const float* wr = W + (size_t)p * SEQL + lane * 8;
    float4 wa = *(const float4*)(wr);
    float4 wz = *(const float4*)(wr + 4);
    float wv[8] = {wa.x, wa.y, wa.z, wa.w, wz.x, wz.y, wz.z, wz.w};
    float c[NB];
    #pragma unroll
    for (int j = 0; j < NB; ++j) {
        const float* bj = tbl + j * SEQL + lane * 8;
        float4 b0 = *(const float4*)bj;
        float4 b1 = *(const float4*)(bj + 4);
        float bb[8] = {b0.x, b0.y, b0.z, b0.w, b1.x, b1.y, b1.z, b1.w};
        float acc = 0.f;
        #pragma unroll
        for (int e = 0; e < 8; ++e) acc += wv[e] * bb[e];
        c[j] = acc;
    }
    #pragma unroll
    for (int m = 1; m < 64; m <<= 1) {
        #pragma unroll
        for (int j = 0; j < NB; ++j) c[j] += __shfl_xor(c[j], m, 64);
    }
    if (lane == 0) {
        #pragma unroll
        for (int j = 0; j < NB; ++j) wb[p * WBPAD + j] = c[j];
    }
}

// ---------------- main kernel: one wave per RU rows ------------------------------
__global__ __launch_bounds__(256)
void detrend_kernel(const float* __restrict__ x, const float* __restrict__ bias,
                    const float* __restrict__ tbl, const float* __restrict__ wb,
                    float* __restrict__ fc, float* __restrict__ resid, int nrows) {
    const int lane = threadIdx.x & 63;
    const int wid  = threadIdx.x >> 6;
    const int wpb  = blockDim.x >> 6;
    const int gw   = blockIdx.x * wpb + wid;
    const int nw   = gridDim.x * wpb;

    // loop-invariant: this lane's 8 basis values per j (72 VGPRs)
    float bas[NB][8];
    #pragma unroll
    for (int j = 0; j < NB; ++j) {
        const float* bj = tbl + j * SEQL + lane * 8;
        float4 b0 = *(const float4*)bj;
        float4 b1 = *(const float4*)(bj + 4);
        bas[j][0] = b0.x; bas[j][1] = b0.y; bas[j][2] = b0.z; bas[j][3] = b0.w;
        bas[j][4] = b1.x; bas[j][5] = b1.y; bas[j][6] = b1.z; bas[j][7] = b1.w;
    }
    // loop-invariant: forecast weights for this lane's output columns
    const int p0 = lane;        // 0..63 (<96, always valid)
    const int p1 = 64 + lane;   // valid for lane<32
    float wb0[NB], wb1[NB], bv0, bv1 = 0.f;
    #pragma unroll
    for (int j = 0; j < NB; ++j) wb0[j] = wb[p0 * WBPAD + j];
    bv0 = bias[p0];
    if (lane < 32) {
        #pragma unroll
        for (int j = 0; j < NB; ++j) wb1[j] = wb[p1 * WBPAD + j];
        bv1 = bias[p1];
    }

    for (int r0 = gw * RU; r0 < nrows; r0 += nw * RU) {
        // ---- load RU rows up front (8 independent dwordx4 loads) ----
        float xv[RU][8];
        #pragma unroll
        for (int u = 0; u < RU; ++u) {
            const float* xr = x + (size_t)(r0 + u) * SEQL + lane * 8;
            float4 xa = *(const float4*)xr;
            float4 xb = *(const float4*)(xr + 4);
            xv[u][0] = xa.x; xv[u][1] = xa.y; xv[u][2] = xa.z; xv[u][3] = xa.w;
            xv[u][4] = xb.x; xv[u][5] = xb.y; xv[u][6] = xb.z; xv[u][7] = xb.w;
        }

        // ---- 9 partial dots per row ----
        float c[RU][NB];
        #pragma unroll
        for (int u = 0; u < RU; ++u)
            #pragma unroll
            for (int j = 0; j < NB; ++j) c[u][j] = 0.f;
        #pragma unroll
        for (int u = 0; u < RU; ++u)
            #pragma unroll
            for (int e = 0; e < 8; ++e)
                #pragma unroll
                for (int j = 0; j < NB; ++j) c[u][j] += xv[u][e] * bas[j][e];

        // ---- full-wave butterfly: 36 independent shuffle+adds per stage ----
        #pragma unroll
        for (int m = 1; m < 64; m <<= 1) {
            #pragma unroll
            for (int u = 0; u < RU; ++u)
                #pragma unroll
                for (int j = 0; j < NB; ++j) c[u][j] += __shfl_xor(c[u][j], m, 64);
        }

        // ---- scale (irfft: DC 1/S, others 2/S) ----
        #pragma unroll
        for (int u = 0; u < RU; ++u) {
            c[u][0] *= (1.0f / SEQL);
            #pragma unroll
            for (int j = 1; j < NB; ++j) c[u][j] *= (2.0f / SEQL);
        }

        // ---- reconstruct trend, write resid (non-temporal) ----
        #pragma unroll
        for (int u = 0; u < RU; ++u) {
            float rv[8];
            #pragma unroll
            for (int e = 0; e < 8; ++e) {
                float t = 0.f;
                #pragma unroll
                for (int j = 0; j < NB; ++j) t += c[u][j] * bas[j][e];
                rv[e] = xv[u][e] - t;
            }
            float* rr = resid + (size_t)(r0 + u) * SEQL + lane * 8;
            fvec4 v0 = {rv[0], rv[1], rv[2], rv[3]};
            fvec4 v1 = {rv[4], rv[5], rv[6], rv[7]};
            __builtin_nontemporal_store(v0, (fvec4*)rr);
            __builtin_nontemporal_store(v1, (fvec4*)(rr + 4));
        }

        // ---- forecast: 96 outputs = rank-9 combo (non-temporal) ----
        #pragma unroll
        for (int u = 0; u < RU; ++u) {
            float* fr = fc + (size_t)(r0 + u) * PREDL;
            float f0 = bv0;
            #pragma unroll
            for (int j = 0; j < NB; ++j) f0 += c[u][j] * wb0[j];
            __builtin_nontemporal_store(f0, fr + p0);
            if (lane < 32) {
                float f1 = bv1;
                #pragma unroll
                for (int j = 0; j < NB; ++j) f1 += c[u][j] * wb1[j];
                __builtin_nontemporal_store(f1, fr + p1);
            }
        }
    }
}

extern "C" void kernel_launch(void* const* d_in, const int* in_sizes, int n_in,
                              void* d_out, int out_size, void* d_ws, size_t ws_size,
                              hipStream_t stream) {
    const float* x = (const float*)d_in[0];
    const float* W = (const float*)d_in[1];
    const float* b = (const float*)d_in[2];
    float* fc = (float*)d_out;
    const int nrows = in_sizes[0] / SEQL;            // 64*1024 = 65536
    float* resid = fc + (size_t)nrows * PREDL;       // outputs concatenated flat
    float* tbl = (float*)d_ws;                       // 9*512 floats
    float* wb  = tbl + NB * SEQL;                    // 96*12 floats

    hipLaunchKernelGGL(basis_kernel, dim3(1), dim3(SEQL), 0, stream, tbl);
    hipLaunchKernelGGL(wb_kernel, dim3(PREDL), dim3(64), 0, stream, W, tbl, wb);
    hipLaunchKernelGGL(detrend_kernel, dim3(2048), dim3(256), 0, stream,
                       x, b, tbl, wb, fc, resid, nrows);
}